// Round 6
// baseline (251.444 us; speedup 1.0000x reference)
//
#include <hip/hip_runtime.h>
#include <math.h>

// Problem constants
//  B=8, C_IN=80, T=1000, D_MODEL=256, D_INNER=512, D_STATE=16, DT_RANK=16,
//  D_CONV=4, N_LABELS=35

// ---- workspace layout (float offsets) ----
#define OFF_W1T   0          // [80][1024]  folded (in_proj@proj) transposed
#define OFF_B1    81920      // [1024]      folded bias
#define OFF_W2S   82944      // [35][512]   (fc_w@out_proj_w) * 1e-3 (mean fold)
#define OFF_AL2   100864     // [512][16]   A = -exp(A_log)
#define OFF_XH    109056     // [8000][512] silu(conv(xh))
#define OFF_SZ    4205056    // [8000][512] silu(z)
#define OFF_PACK  8301056    // [8000][512] float2 (delta, xh)
#define OFF_BC    16493056   // [8000][16]  float2 (B, C)
#define OFF_CHUNK 16749056   // [8ck][8b][16s][512d] float4 (P,q,S1,S2)
#define OFF_DBCP  OFF_CHUNK  // [2ks][8000][48] k2b partials — dead before CHUNK written
#define OFF_ACCDC 18846208   // [8ck][8b][512] partial sums of xh*sz
#define OFF_YBAR  18878976   // [8][512]
#define WS_FLOATS 18883072   // ~75.5 MB

__device__ __forceinline__ float silu_f(float v) {
  return v / (1.f + __expf(-v));
}

// ================= prep: folded weights =================
// W1T[c][n] = sum_m in_proj_w[n][m] * proj_w[m][c]   (M=80,N=1024,K=256)
__global__ __launch_bounds__(256) void prep_w1t(const float* __restrict__ proj_w,
                                                const float* __restrict__ in_proj_w,
                                                float* __restrict__ ws) {
  const int nt = blockIdx.x;          // 16 tiles of 64 n
  const int ct = blockIdx.y;          // 5 tiles of 16 c
  const int n0 = nt * 64, c0 = ct * 16;
  __shared__ float Pl[16 * 68];       // [c][k]
  __shared__ float Il[64 * 68];       // [k][n]
  const int tid = threadIdx.x;
  const int ng = tid & 31, cg = tid >> 5;   // 32 n-groups x2, 8 c-groups x2
  float acc[2][2] = {{0.f, 0.f}, {0.f, 0.f}};
  for (int kc = 0; kc < 256; kc += 64) {
    __syncthreads();
    for (int i = tid; i < 16 * 64; i += 256) {
      int k = i >> 4, c = i & 15;
      Pl[c * 68 + k] = proj_w[(kc + k) * 80 + c0 + c];
    }
    for (int i = tid; i < 64 * 64; i += 256) {
      int n = i >> 6, k = i & 63;
      Il[k * 68 + n] = in_proj_w[(n0 + n) * 256 + kc + k];
    }
    __syncthreads();
    for (int k = 0; k < 64; ++k) {
      float p0 = Pl[(cg * 2 + 0) * 68 + k];
      float p1 = Pl[(cg * 2 + 1) * 68 + k];
      float2 iv = *(const float2*)&Il[k * 68 + ng * 2];
      acc[0][0] = fmaf(p0, iv.x, acc[0][0]);
      acc[0][1] = fmaf(p0, iv.y, acc[0][1]);
      acc[1][0] = fmaf(p1, iv.x, acc[1][0]);
      acc[1][1] = fmaf(p1, iv.y, acc[1][1]);
    }
  }
  for (int r = 0; r < 2; ++r)
    for (int q = 0; q < 2; ++q)
      ws[OFF_W1T + (c0 + cg * 2 + r) * 1024 + n0 + ng * 2 + q] = acc[r][q];
}

// b1, W2s (scaled by 1/T), A
__global__ __launch_bounds__(256) void prep_small(const float* __restrict__ proj_b,
                                                  const float* __restrict__ in_proj_w,
                                                  const float* __restrict__ fc_w,
                                                  const float* __restrict__ out_proj_w,
                                                  const float* __restrict__ A_log,
                                                  float* __restrict__ ws) {
  int idx = blockIdx.x * 256 + threadIdx.x;
  if (idx < 1024) {
    float s = 0.f;
    for (int m = 0; m < 256; ++m) s = fmaf(in_proj_w[idx * 256 + m], proj_b[m], s);
    ws[OFF_B1 + idx] = s;
  } else if (idx < 1024 + 17920) {
    int j = idx - 1024;
    int n = j / 512, d = j - n * 512;   // consecutive threads -> consecutive d (coalesced)
    float s = 0.f;
    for (int m = 0; m < 256; ++m) s = fmaf(fc_w[n * 256 + m], out_proj_w[m * 512 + d], s);
    ws[OFF_W2S + j] = s * 1e-3f;        // fold mean over T=1000
  } else if (idx < 1024 + 17920 + 8192) {
    int j = idx - (1024 + 17920);
    ws[OFF_AL2 + j] = -expf(A_log[j]);
  }
}

// ================= K1: xz = X @ W1T + b1, LDS-free, conv in registers ======
// Block = 256 threads = 256 consecutive n columns; 20-slot t-window
// (t0-4 .. t0+15) identical for the whole block (blockIdx-derived only)
// => x row addresses wave-uniform => SMEM s_load. W1T per-lane coalesced.
// grid (4 n-tiles, 63 t-chunks of 16, 8 b) = 2016 blocks (~8/CU).
template <bool L, bool R>
__device__ __forceinline__ void k1_body(const float* __restrict__ x,
                                        const float* __restrict__ conv_w,
                                        const float* __restrict__ conv_b,
                                        float* __restrict__ ws,
                                        int nt, int tch, int b) {
  const int tid = threadIdx.x;
  const int n = nt * 256 + tid;        // global n column (0..1023)
  const int t0 = tch * 16;
  const int tbase = t0 - 4;            // 16B-aligned; acc[j] = xz at t=tbase+j

  float acc[20];
  {
    const float b1v = ws[OFF_B1 + n];
#pragma unroll
    for (int j = 0; j < 20; ++j) acc[j] = b1v;
  }

  const float* __restrict__ w1t = ws + OFF_W1T;
  for (int kc = 0; kc < 80; kc += 8) {
    float wreg[8];
#pragma unroll
    for (int kk = 0; kk < 8; ++kk)
      wreg[kk] = w1t[(kc + kk) * 1024 + n];          // per-lane coalesced
#pragma unroll
    for (int kk = 0; kk < 8; ++kk) {
      const float* xrow = x + (b * 80 + kc + kk) * 1000 + tbase;  // uniform addr
      const float w = wreg[kk];
#pragma unroll
      for (int g = 0; g < 5; ++g) {
        float4 xv;
        if (L && g == 0) {
          // t = -4..-1 -> zero pad
          xv = make_float4(0.f, 0.f, 0.f, 0.f);
        } else if (R && g >= 3) {
          int tg = tbase + g * 4;
          xv.x = (tg + 0 <= 999) ? xrow[g * 4 + 0] : 0.f;
          xv.y = (tg + 1 <= 999) ? xrow[g * 4 + 1] : 0.f;
          xv.z = (tg + 2 <= 999) ? xrow[g * 4 + 2] : 0.f;
          xv.w = (tg + 3 <= 999) ? xrow[g * 4 + 3] : 0.f;
        } else {
          xv = *(const float4*)(xrow + g * 4);       // uniform -> s_load_dwordx4
        }
        acc[g * 4 + 0] = fmaf(xv.x, w, acc[g * 4 + 0]);
        acc[g * 4 + 1] = fmaf(xv.y, w, acc[g * 4 + 1]);
        acc[g * 4 + 2] = fmaf(xv.z, w, acc[g * 4 + 2]);
        acc[g * 4 + 3] = fmaf(xv.w, w, acc[g * 4 + 3]);
      }
    }
  }

  if (L) {
    // reference pads the PROJECTED sequence with zeros: xz[t<0] = 0
    acc[0] = 0.f; acc[1] = 0.f; acc[2] = 0.f; acc[3] = 0.f;
  }

  if (nt < 2) {
    // h-half: causal conv (taps t-3..t) + silu
    const int d = n;
    const float4 cw = *(const float4*)&conv_w[d * 4];
    const float cb = conv_b[d];
#pragma unroll
    for (int i = 0; i < 16; ++i) {
      int t = t0 + i;
      if (!R || t < 1000) {
        float v = cb;
        v = fmaf(cw.x, acc[i + 1], v);   // xz[t-3]
        v = fmaf(cw.y, acc[i + 2], v);   // xz[t-2]
        v = fmaf(cw.z, acc[i + 3], v);   // xz[t-1]
        v = fmaf(cw.w, acc[i + 4], v);   // xz[t]
        ws[OFF_XH + (b * 1000 + t) * 512 + d] = silu_f(v);
      }
    }
  } else {
    const int d0 = n - 512;
#pragma unroll
    for (int i = 0; i < 16; ++i) {
      int t = t0 + i;
      if (!R || t < 1000)
        ws[OFF_SZ + (b * 1000 + t) * 512 + d0] = silu_f(acc[i + 4]);
    }
  }
}

__global__ __launch_bounds__(256) void k1_xz(const float* __restrict__ x,
                                             const float* __restrict__ conv_w,
                                             const float* __restrict__ conv_b,
                                             float* __restrict__ ws) {
  const int nt  = blockIdx.x;   // 4 tiles of 256 n
  const int tch = blockIdx.y;   // 63 chunks of 16 t
  const int b   = blockIdx.z;
  if (tch == 0)       k1_body<true,  false>(x, conv_w, conv_b, ws, nt, tch, b);
  else if (tch == 62) k1_body<false, true >(x, conv_w, conv_b, ws, nt, tch, b);
  else                k1_body<false, false>(x, conv_w, conv_b, ws, nt, tch, b);
}

// ================= K2b: dbc partials = xh @ x_proj_w.T (split-K x2) =========
// grid (500 row-tiles of 16, 2 K-halves). 1000 blocks.
__global__ __launch_bounds__(256) void k2b_dbc(const float* __restrict__ x_proj_w,
                                               float* __restrict__ ws) {
  const int row0 = blockIdx.x * 16;
  const int ks   = blockIdx.y;          // K half
  const int k0   = ks * 256;
  __shared__ float Xl[16 * 68];
  __shared__ float Wl[48 * 68];
  const int tid = threadIdx.x;
  const int ng = tid & 15, rg = tid >> 4;   // 16 n-groups x3, 16 rows x1
  float acc[3] = {0.f, 0.f, 0.f};
  for (int kc = 0; kc < 256; kc += 64) {
    __syncthreads();
    for (int i = tid; i < 16 * 64; i += 256) {
      int r = i >> 6, c = i & 63;
      Xl[r * 68 + c] = ws[OFF_XH + (row0 + r) * 512 + k0 + kc + c];
    }
    for (int i = tid; i < 48 * 64; i += 256) {
      int r = i >> 6, c = i & 63;
      Wl[r * 68 + c] = x_proj_w[r * 512 + k0 + kc + c];
    }
    __syncthreads();
    for (int c = 0; c < 64; c += 4) {
      float4 xa = *(const float4*)&Xl[rg * 68 + c];
      float4 w0 = *(const float4*)&Wl[(ng * 3 + 0) * 68 + c];
      float4 w1 = *(const float4*)&Wl[(ng * 3 + 1) * 68 + c];
      float4 w2 = *(const float4*)&Wl[(ng * 3 + 2) * 68 + c];
      acc[0] += xa.x*w0.x + xa.y*w0.y + xa.z*w0.z + xa.w*w0.w;
      acc[1] += xa.x*w1.x + xa.y*w1.y + xa.z*w1.z + xa.w*w1.w;
      acc[2] += xa.x*w2.x + xa.y*w2.y + xa.z*w2.z + xa.w*w2.w;
    }
  }
  for (int n = 0; n < 3; ++n)
    ws[OFF_DBCP + ks * 384000 + (row0 + rg) * 48 + ng * 3 + n] = acc[n];
}

// ================= K2c: delta=softplus(dt@dtw+b); write pack(delta,xh), BC ==
__global__ __launch_bounds__(256) void k2c_pack(const float* __restrict__ dt_proj_w,
                                                const float* __restrict__ dt_proj_b,
                                                float* __restrict__ ws) {
  const int tb = blockIdx.x;   // 125 tiles of 8 t
  const int b  = blockIdx.y;
  const int tid = threadIdx.x;
  __shared__ float dbcl[8 * 48];
  for (int i = tid; i < 8 * 48; i += 256) {
    int tt = i / 48, c = i - tt * 48;
    int row = b * 1000 + tb * 8 + tt;
    dbcl[i] = ws[OFF_DBCP + row * 48 + c] + ws[OFF_DBCP + 384000 + row * 48 + c];
  }
  __syncthreads();
  if (tid < 128) {
    int tt = tid >> 4, s = tid & 15;
    int row = b * 1000 + tb * 8 + tt;
    *(float2*)&ws[OFF_BC + (row * 16 + s) * 2] =
        make_float2(dbcl[tt * 48 + 16 + s], dbcl[tt * 48 + 32 + s]);
  }
  for (int dd = tid; dd < 512; dd += 256) {
    const float4* wp = (const float4*)(dt_proj_w + dd * 16);
    float4 w0 = wp[0], w1 = wp[1], w2 = wp[2], w3 = wp[3];
    float bias = dt_proj_b[dd];
#pragma unroll
    for (int tt = 0; tt < 8; ++tt) {
      int row = b * 1000 + tb * 8 + tt;
      const float* dr = &dbcl[tt * 48];
      float lin = bias;
      lin = fmaf(dr[0],  w0.x, lin); lin = fmaf(dr[1],  w0.y, lin);
      lin = fmaf(dr[2],  w0.z, lin); lin = fmaf(dr[3],  w0.w, lin);
      lin = fmaf(dr[4],  w1.x, lin); lin = fmaf(dr[5],  w1.y, lin);
      lin = fmaf(dr[6],  w1.z, lin); lin = fmaf(dr[7],  w1.w, lin);
      lin = fmaf(dr[8],  w2.x, lin); lin = fmaf(dr[9],  w2.y, lin);
      lin = fmaf(dr[10], w2.z, lin); lin = fmaf(dr[11], w2.w, lin);
      lin = fmaf(dr[12], w3.x, lin); lin = fmaf(dr[13], w3.y, lin);
      lin = fmaf(dr[14], w3.z, lin); lin = fmaf(dr[15], w3.w, lin);
      float delta = fmaxf(lin, 0.f) + log1pf(__expf(-fabsf(lin)));  // softplus
      float xh = ws[OFF_XH + row * 512 + dd];
      *(float2*)&ws[OFF_PACK + (row * 512 + dd) * 2] = make_float2(delta, xh);
    }
  }
}

// ================= K3: chunked scan pass 1 (d-major, s-split x2) ============
// block 512 = 64 d-lanes x 8 waves; ONE s-chain per thread (s = sh*8 + wv).
// grid (8 dg, 16 = 8 ck x 2 sh, 8 b) = 1024 blocks x 8 waves = 32 waves/CU.
// BC (this half) staged in LDS; pack/sz in 5-wide double-buffered groups.
#define K3_LOADG(P, Z, g)                                   \
  {                                                         \
    const int _b = (g) * 5;                                 \
    _Pragma("unroll") for (int _u = 0; _u < 5; ++_u) {      \
      P[_u] = packp[(_b + _u) * 512];                       \
      Z[_u] = szp[(_b + _u) * 512];                         \
    }                                                       \
  }
#define K3_COMPG(P, Z, g)                                                   \
  {                                                                         \
    const int _b = (g) * 5;                                                 \
    _Pragma("unroll") for (int _u = 0; _u < 5; ++_u) {                      \
      float2 p = P[_u];                                                     \
      float sz = Z[_u];                                                     \
      float2 bc = *(const float2*)&bcl[(_b + _u) * 16 + wv * 2];            \
      float e = __expf(p.x * a);                                            \
      cp *= e;                                                              \
      h = fmaf(e, h, (p.x * p.y) * bc.x);                                   \
      float cs = bc.y * sz;                                                 \
      S1 = fmaf(h, cs, S1);                                                 \
      S2 = fmaf(cp, cs, S2);                                                \
      xacc = fmaf(p.y, sz, xacc);                                           \
    }                                                                       \
  }

__global__ __launch_bounds__(512) void k3_scan1(float* __restrict__ ws) {
  const int dg = blockIdx.x;          // 8 groups of 64 d
  const int ck = blockIdx.y & 7;      // 8 chunks of 125 t
  const int sh = blockIdx.y >> 3;     // 2 s-halves
  const int b  = blockIdx.z;
  const int tid = threadIdx.x;
  const int lane = tid & 63;          // d within group
  const int wv = tid >> 6;            // 0..7
  const int s  = sh * 8 + wv;
  const int d = dg * 64 + lane;
  const float a = ws[OFF_AL2 + d * 16 + s];
  const int rowbase = b * 1000 + ck * 125;
  __shared__ __align__(16) float bcl[2000];   // [125 t][8 s][2] (this half)
  for (int i = tid; i < 2000; i += 512)
    bcl[i] = ws[OFF_BC + rowbase * 32 + (i >> 4) * 32 + sh * 16 + (i & 15)];
  __syncthreads();
  const float2* __restrict__ packp = (const float2*)(ws + OFF_PACK) + rowbase * 512 + d;
  const float*  __restrict__ szp   = ws + OFF_SZ + rowbase * 512 + d;
  float h = 0.f, cp = 1.f, S1 = 0.f, S2 = 0.f, xacc = 0.f;
  float2 PA[5], PB[5];
  float  ZA[5], ZB[5];
  K3_LOADG(PA, ZA, 0);
  for (int g = 0; g < 12; ++g) {
    K3_LOADG(PB, ZB, 2 * g + 1);
    K3_COMPG(PA, ZA, 2 * g);
    K3_LOADG(PA, ZA, 2 * g + 2);
    K3_COMPG(PB, ZB, 2 * g + 1);
  }
  K3_COMPG(PA, ZA, 24);
  {
    int idx = ((ck * 8 + b) * 16 + s) * 512 + d;   // [ck][b][s][d] — coalesced
    *(float4*)&ws[OFF_CHUNK + idx * 4] = make_float4(cp, h, S1, S2);
  }
  if (sh == 0 && wv == 0) ws[OFF_ACCDC + (ck * 8 + b) * 512 + d] = xacc;
}

// ================= K4: combine chunks + s-reduce -> ybar =================
// grid (32 dg, 8 b) = 256 blocks; block 256 = 16 d x 16 s.
__global__ __launch_bounds__(256) void k4_scan2(const float* __restrict__ Dvec,
                                                float* __restrict__ ws) {
  const int dg = blockIdx.x;   // 32 groups of 16 d
  const int b  = blockIdx.y;
  const int tid = threadIdx.x;
  const int dl = tid & 15, s = tid >> 4;
  const int d = dg * 16 + dl;
  const int lane = tid & 63, wv = tid >> 6;
  float h = 0.f, y = 0.f;
#pragma unroll
  for (int k = 0; k < 8; ++k) {
    const float4 f = *(const float4*)&ws[OFF_CHUNK + (((k * 8 + b) * 16 + s) * 512 + d) * 4];
    y = fmaf(f.w, h, y + f.z);   // S1 + S2*h_in
    h = fmaf(f.x, h, f.y);       // P*h_in + q
  }
  // reduce over the 4 s-values within each wave (lane bits 4,5)
  y += __shfl_xor(y, 16);
  y += __shfl_xor(y, 32);
  __shared__ float ys[4][16];
  if (lane < 16) ys[wv][dl] = y;
  __syncthreads();
  if (tid < 16) {
    float yt = ys[0][tid] + ys[1][tid] + ys[2][tid] + ys[3][tid];
    float acc = 0.f;
#pragma unroll
    for (int k = 0; k < 8; ++k) acc += ws[OFF_ACCDC + (k * 8 + b) * 512 + dg * 16 + tid];
    int dd = dg * 16 + tid;
    ws[OFF_YBAR + b * 512 + dd] = yt + Dvec[dd] * acc;
  }
}

// ================= K5: out = ybar @ W2s.T + fc_b =================
__global__ __launch_bounds__(64) void k5_out(const float* __restrict__ fc_b,
                                             const float* __restrict__ ws,
                                             float* __restrict__ out) {
  const int b = blockIdx.x;
  const int n = threadIdx.x;
  if (n >= 35) return;
  const float* yb = ws + OFF_YBAR + b * 512;
  const float* w  = ws + OFF_W2S + n * 512;
  float sum = 0.f;
#pragma unroll 8
  for (int k = 0; k < 512; ++k) sum = fmaf(yb[k], w[k], sum);
  out[b * 35 + n] = sum + fc_b[n];
}

extern "C" void kernel_launch(void* const* d_in, const int* in_sizes, int n_in,
                              void* d_out, int out_size, void* d_ws, size_t ws_size,
                              hipStream_t stream) {
  const float* x          = (const float*)d_in[0];
  const float* proj_w     = (const float*)d_in[1];
  const float* proj_b     = (const float*)d_in[2];
  const float* in_proj_w  = (const float*)d_in[3];
  const float* conv_w     = (const float*)d_in[4];
  const float* conv_b     = (const float*)d_in[5];
  const float* x_proj_w   = (const float*)d_in[6];
  const float* dt_proj_w  = (const float*)d_in[7];
  const float* dt_proj_b  = (const float*)d_in[8];
  const float* A_log      = (const float*)d_in[9];
  const float* Dvec       = (const float*)d_in[10];
  const float* out_proj_w = (const float*)d_in[11];
  const float* fc_w       = (const float*)d_in[12];
  const float* fc_b       = (const float*)d_in[13];
  float* ws  = (float*)d_ws;
  float* out = (float*)d_out;
  if (ws_size < (size_t)WS_FLOATS * sizeof(float)) return;  // need ~76 MB scratch

  prep_w1t  <<<dim3(16, 5),    256, 0, stream>>>(proj_w, in_proj_w, ws);
  prep_small<<<106,            256, 0, stream>>>(proj_b, in_proj_w, fc_w, out_proj_w, A_log, ws);
  k1_xz     <<<dim3(4, 63, 8), 256, 0, stream>>>(x, conv_w, conv_b, ws);
  k2b_dbc   <<<dim3(500, 2),   256, 0, stream>>>(x_proj_w, ws);
  k2c_pack  <<<dim3(125, 8),   256, 0, stream>>>(dt_proj_w, dt_proj_b, ws);
  k3_scan1  <<<dim3(8, 16, 8), 512, 0, stream>>>(ws);
  k4_scan2  <<<dim3(32, 8),    256, 0, stream>>>(Dvec, ws);
  k5_out    <<<8,              64,  0, stream>>>(fc_b, ws, out);
}

// Round 7
// 164.335 us; speedup vs baseline: 1.5301x; 1.5301x over previous
//
#include <hip/hip_runtime.h>
#include <math.h>

// Problem constants
//  B=8, C_IN=80, T=1000, D_MODEL=256, D_INNER=512, D_STATE=16, DT_RANK=16,
//  D_CONV=4, N_LABELS=35

// ---- workspace layout (float offsets) ----
#define OFF_W1T   0          // [80][1024]  folded (in_proj@proj) transposed
#define OFF_B1    81920      // [1024]      folded bias
#define OFF_W2S   82944      // [35][512]   (fc_w@out_proj_w) * 1e-3 (mean fold)
#define OFF_AL2   100864     // [512][16]   A = -exp(A_log)
#define OFF_XH    109056     // [8000][512] silu(conv(xh)) — DEAD after k2c; reused for CHUNK ck<8 + ACC16
#define OFF_SZ    4205056    // [8000][512] silu(z)
#define OFF_PACK  8301056    // [8000][512] float2 (delta, xh)
#define OFF_BC    16493056   // [8000][16]  float2 (B, C)
#define OFF_CHUNK 16749056   // CHUNK ck>=8 region (2,097,152 floats)
#define OFF_DBCP  OFF_CHUNK  // [2ks][8000][48] k2b partials — dead before k3 writes here
#define OFF_YBAR  18878976   // [8][512]
#define WS_FLOATS 18883072   // ~75.5 MB

// 16 t-chunks: per-chunk block = 8b*16s*512d*4 floats
#define CK_FLOATS 262144
#define CHUNK_BASE(ck) ((ck) < 8 ? (OFF_XH + (ck) * CK_FLOATS) \
                                 : (OFF_CHUNK + ((ck) - 8) * CK_FLOATS))
#define OFF_ACC16 (OFF_XH + 2097152)   // [16ck][8b][512d] — inside dead XH region

__device__ __forceinline__ float silu_f(float v) {
  return v / (1.f + __expf(-v));
}

// ================= prep: folded weights =================
// W1T[c][n] = sum_m in_proj_w[n][m] * proj_w[m][c]   (M=80,N=1024,K=256)
__global__ __launch_bounds__(256) void prep_w1t(const float* __restrict__ proj_w,
                                                const float* __restrict__ in_proj_w,
                                                float* __restrict__ ws) {
  const int nt = blockIdx.x;          // 16 tiles of 64 n
  const int ct = blockIdx.y;          // 5 tiles of 16 c
  const int n0 = nt * 64, c0 = ct * 16;
  __shared__ float Pl[16 * 68];       // [c][k]
  __shared__ float Il[64 * 68];       // [k][n]
  const int tid = threadIdx.x;
  const int ng = tid & 31, cg = tid >> 5;   // 32 n-groups x2, 8 c-groups x2
  float acc[2][2] = {{0.f, 0.f}, {0.f, 0.f}};
  for (int kc = 0; kc < 256; kc += 64) {
    __syncthreads();
    for (int i = tid; i < 16 * 64; i += 256) {
      int k = i >> 4, c = i & 15;
      Pl[c * 68 + k] = proj_w[(kc + k) * 80 + c0 + c];
    }
    for (int i = tid; i < 64 * 64; i += 256) {
      int n = i >> 6, k = i & 63;
      Il[k * 68 + n] = in_proj_w[(n0 + n) * 256 + kc + k];
    }
    __syncthreads();
    for (int k = 0; k < 64; ++k) {
      float p0 = Pl[(cg * 2 + 0) * 68 + k];
      float p1 = Pl[(cg * 2 + 1) * 68 + k];
      float2 iv = *(const float2*)&Il[k * 68 + ng * 2];
      acc[0][0] = fmaf(p0, iv.x, acc[0][0]);
      acc[0][1] = fmaf(p0, iv.y, acc[0][1]);
      acc[1][0] = fmaf(p1, iv.x, acc[1][0]);
      acc[1][1] = fmaf(p1, iv.y, acc[1][1]);
    }
  }
  for (int r = 0; r < 2; ++r)
    for (int q = 0; q < 2; ++q)
      ws[OFF_W1T + (c0 + cg * 2 + r) * 1024 + n0 + ng * 2 + q] = acc[r][q];
}

// b1, W2s (scaled by 1/T), A
__global__ __launch_bounds__(256) void prep_small(const float* __restrict__ proj_b,
                                                  const float* __restrict__ in_proj_w,
                                                  const float* __restrict__ fc_w,
                                                  const float* __restrict__ out_proj_w,
                                                  const float* __restrict__ A_log,
                                                  float* __restrict__ ws) {
  int idx = blockIdx.x * 256 + threadIdx.x;
  if (idx < 1024) {
    float s = 0.f;
    for (int m = 0; m < 256; ++m) s = fmaf(in_proj_w[idx * 256 + m], proj_b[m], s);
    ws[OFF_B1 + idx] = s;
  } else if (idx < 1024 + 17920) {
    int j = idx - 1024;
    int n = j / 512, d = j - n * 512;   // consecutive threads -> consecutive d (coalesced)
    float s = 0.f;
    for (int m = 0; m < 256; ++m) s = fmaf(fc_w[n * 256 + m], out_proj_w[m * 512 + d], s);
    ws[OFF_W2S + j] = s * 1e-3f;        // fold mean over T=1000
  } else if (idx < 1024 + 17920 + 8192) {
    int j = idx - (1024 + 17920);
    ws[OFF_AL2 + j] = -expf(A_log[j]);
  }
}

// ================= K1: xz = X @ W1T + b1, LDS-free, conv in registers ======
// Block = 256 threads = 256 consecutive n columns; 20-slot t-window
// (t0-4 .. t0+15) identical for the whole block (blockIdx-derived only)
// => x row addresses wave-uniform => SMEM s_load. W1T per-lane coalesced.
// grid (4 n-tiles, 63 t-chunks of 16, 8 b) = 2016 blocks (~8/CU).
template <bool L, bool R>
__device__ __forceinline__ void k1_body(const float* __restrict__ x,
                                        const float* __restrict__ conv_w,
                                        const float* __restrict__ conv_b,
                                        float* __restrict__ ws,
                                        int nt, int tch, int b) {
  const int tid = threadIdx.x;
  const int n = nt * 256 + tid;        // global n column (0..1023)
  const int t0 = tch * 16;
  const int tbase = t0 - 4;            // 16B-aligned; acc[j] = xz at t=tbase+j

  float acc[20];
  {
    const float b1v = ws[OFF_B1 + n];
#pragma unroll
    for (int j = 0; j < 20; ++j) acc[j] = b1v;
  }

  const float* __restrict__ w1t = ws + OFF_W1T;
  for (int kc = 0; kc < 80; kc += 8) {
    float wreg[8];
#pragma unroll
    for (int kk = 0; kk < 8; ++kk)
      wreg[kk] = w1t[(kc + kk) * 1024 + n];          // per-lane coalesced
#pragma unroll
    for (int kk = 0; kk < 8; ++kk) {
      const float* xrow = x + (b * 80 + kc + kk) * 1000 + tbase;  // uniform addr
      const float w = wreg[kk];
#pragma unroll
      for (int g = 0; g < 5; ++g) {
        float4 xv;
        if (L && g == 0) {
          // t = -4..-1 -> zero pad
          xv = make_float4(0.f, 0.f, 0.f, 0.f);
        } else if (R && g >= 3) {
          int tg = tbase + g * 4;
          xv.x = (tg + 0 <= 999) ? xrow[g * 4 + 0] : 0.f;
          xv.y = (tg + 1 <= 999) ? xrow[g * 4 + 1] : 0.f;
          xv.z = (tg + 2 <= 999) ? xrow[g * 4 + 2] : 0.f;
          xv.w = (tg + 3 <= 999) ? xrow[g * 4 + 3] : 0.f;
        } else {
          xv = *(const float4*)(xrow + g * 4);       // uniform -> s_load_dwordx4
        }
        acc[g * 4 + 0] = fmaf(xv.x, w, acc[g * 4 + 0]);
        acc[g * 4 + 1] = fmaf(xv.y, w, acc[g * 4 + 1]);
        acc[g * 4 + 2] = fmaf(xv.z, w, acc[g * 4 + 2]);
        acc[g * 4 + 3] = fmaf(xv.w, w, acc[g * 4 + 3]);
      }
    }
  }

  if (L) {
    // reference pads the PROJECTED sequence with zeros: xz[t<0] = 0
    acc[0] = 0.f; acc[1] = 0.f; acc[2] = 0.f; acc[3] = 0.f;
  }

  if (nt < 2) {
    // h-half: causal conv (taps t-3..t) + silu
    const int d = n;
    const float4 cw = *(const float4*)&conv_w[d * 4];
    const float cb = conv_b[d];
#pragma unroll
    for (int i = 0; i < 16; ++i) {
      int t = t0 + i;
      if (!R || t < 1000) {
        float v = cb;
        v = fmaf(cw.x, acc[i + 1], v);   // xz[t-3]
        v = fmaf(cw.y, acc[i + 2], v);   // xz[t-2]
        v = fmaf(cw.z, acc[i + 3], v);   // xz[t-1]
        v = fmaf(cw.w, acc[i + 4], v);   // xz[t]
        ws[OFF_XH + (b * 1000 + t) * 512 + d] = silu_f(v);
      }
    }
  } else {
    const int d0 = n - 512;
#pragma unroll
    for (int i = 0; i < 16; ++i) {
      int t = t0 + i;
      if (!R || t < 1000)
        ws[OFF_SZ + (b * 1000 + t) * 512 + d0] = silu_f(acc[i + 4]);
    }
  }
}

__global__ __launch_bounds__(256) void k1_xz(const float* __restrict__ x,
                                             const float* __restrict__ conv_w,
                                             const float* __restrict__ conv_b,
                                             float* __restrict__ ws) {
  const int nt  = blockIdx.x;   // 4 tiles of 256 n
  const int tch = blockIdx.y;   // 63 chunks of 16 t
  const int b   = blockIdx.z;
  if (tch == 0)       k1_body<true,  false>(x, conv_w, conv_b, ws, nt, tch, b);
  else if (tch == 62) k1_body<false, true >(x, conv_w, conv_b, ws, nt, tch, b);
  else                k1_body<false, false>(x, conv_w, conv_b, ws, nt, tch, b);
}

// ================= K2b: dbc partials = xh @ x_proj_w.T (split-K x2) =========
// grid (500 row-tiles of 16, 2 K-halves). 1000 blocks.
__global__ __launch_bounds__(256) void k2b_dbc(const float* __restrict__ x_proj_w,
                                               float* __restrict__ ws) {
  const int row0 = blockIdx.x * 16;
  const int ks   = blockIdx.y;          // K half
  const int k0   = ks * 256;
  __shared__ float Xl[16 * 68];
  __shared__ float Wl[48 * 68];
  const int tid = threadIdx.x;
  const int ng = tid & 15, rg = tid >> 4;   // 16 n-groups x3, 16 rows x1
  float acc[3] = {0.f, 0.f, 0.f};
  for (int kc = 0; kc < 256; kc += 64) {
    __syncthreads();
    for (int i = tid; i < 16 * 64; i += 256) {
      int r = i >> 6, c = i & 63;
      Xl[r * 68 + c] = ws[OFF_XH + (row0 + r) * 512 + k0 + kc + c];
    }
    for (int i = tid; i < 48 * 64; i += 256) {
      int r = i >> 6, c = i & 63;
      Wl[r * 68 + c] = x_proj_w[r * 512 + k0 + kc + c];
    }
    __syncthreads();
    for (int c = 0; c < 64; c += 4) {
      float4 xa = *(const float4*)&Xl[rg * 68 + c];
      float4 w0 = *(const float4*)&Wl[(ng * 3 + 0) * 68 + c];
      float4 w1 = *(const float4*)&Wl[(ng * 3 + 1) * 68 + c];
      float4 w2 = *(const float4*)&Wl[(ng * 3 + 2) * 68 + c];
      acc[0] += xa.x*w0.x + xa.y*w0.y + xa.z*w0.z + xa.w*w0.w;
      acc[1] += xa.x*w1.x + xa.y*w1.y + xa.z*w1.z + xa.w*w1.w;
      acc[2] += xa.x*w2.x + xa.y*w2.y + xa.z*w2.z + xa.w*w2.w;
    }
  }
  for (int n = 0; n < 3; ++n)
    ws[OFF_DBCP + ks * 384000 + (row0 + rg) * 48 + ng * 3 + n] = acc[n];
}

// ================= K2c: delta=softplus(dt@dtw+b); write pack(delta,xh), BC ==
__global__ __launch_bounds__(256) void k2c_pack(const float* __restrict__ dt_proj_w,
                                                const float* __restrict__ dt_proj_b,
                                                float* __restrict__ ws) {
  const int tb = blockIdx.x;   // 125 tiles of 8 t
  const int b  = blockIdx.y;
  const int tid = threadIdx.x;
  __shared__ float dbcl[8 * 48];
  for (int i = tid; i < 8 * 48; i += 256) {
    int tt = i / 48, c = i - tt * 48;
    int row = b * 1000 + tb * 8 + tt;
    dbcl[i] = ws[OFF_DBCP + row * 48 + c] + ws[OFF_DBCP + 384000 + row * 48 + c];
  }
  __syncthreads();
  if (tid < 128) {
    int tt = tid >> 4, s = tid & 15;
    int row = b * 1000 + tb * 8 + tt;
    *(float2*)&ws[OFF_BC + (row * 16 + s) * 2] =
        make_float2(dbcl[tt * 48 + 16 + s], dbcl[tt * 48 + 32 + s]);
  }
  for (int dd = tid; dd < 512; dd += 256) {
    const float4* wp = (const float4*)(dt_proj_w + dd * 16);
    float4 w0 = wp[0], w1 = wp[1], w2 = wp[2], w3 = wp[3];
    float bias = dt_proj_b[dd];
#pragma unroll
    for (int tt = 0; tt < 8; ++tt) {
      int row = b * 1000 + tb * 8 + tt;
      const float* dr = &dbcl[tt * 48];
      float lin = bias;
      lin = fmaf(dr[0],  w0.x, lin); lin = fmaf(dr[1],  w0.y, lin);
      lin = fmaf(dr[2],  w0.z, lin); lin = fmaf(dr[3],  w0.w, lin);
      lin = fmaf(dr[4],  w1.x, lin); lin = fmaf(dr[5],  w1.y, lin);
      lin = fmaf(dr[6],  w1.z, lin); lin = fmaf(dr[7],  w1.w, lin);
      lin = fmaf(dr[8],  w2.x, lin); lin = fmaf(dr[9],  w2.y, lin);
      lin = fmaf(dr[10], w2.z, lin); lin = fmaf(dr[11], w2.w, lin);
      lin = fmaf(dr[12], w3.x, lin); lin = fmaf(dr[13], w3.y, lin);
      lin = fmaf(dr[14], w3.z, lin); lin = fmaf(dr[15], w3.w, lin);
      float delta = fmaxf(lin, 0.f) + log1pf(__expf(-fabsf(lin)));  // softplus
      float xh = ws[OFF_XH + row * 512 + dd];
      *(float2*)&ws[OFF_PACK + (row * 512 + dd) * 2] = make_float2(delta, xh);
    }
  }
}

// ================= K3: chunked scan pass 1 (d-major, 16 t-chunks) ===========
// block 512 = 64 d-lanes x 8 waves; TWO s-chains per thread (s = wv*2+{0,1}).
// grid (8 dg, 16 ck, 8 b) = 1024 blocks x 8 waves = 32 waves/CU.
// The 8 waves of a block read IDENTICAL pack/sz lines -> L1-served after
// first toucher. BC chunk staged in LDS. Simple rolled loop (compiler
// pipelines; manual 5-wide dbuf inflated VGPR to 128 in round 5).
__global__ __launch_bounds__(512) void k3_scan1(float* __restrict__ ws) {
  const int dg = blockIdx.x;          // 8 groups of 64 d
  const int ck = blockIdx.y;          // 16 t-chunks (63 for ck<8, else 62)
  const int b  = blockIdx.z;
  const int tid = threadIdx.x;
  const int lane = tid & 63;          // d within group
  const int wv = tid >> 6;            // 0..7; s = wv*2 + {0,1}
  const int d = dg * 64 + lane;
  const float2 av = *(const float2*)&ws[OFF_AL2 + d * 16 + wv * 2];
  const float a0 = av.x, a1 = av.y;
  const int nt = (ck < 8) ? 63 : 62;
  const int tstart = (ck < 8) ? 63 * ck : 62 * ck + 8;
  const int rowbase = b * 1000 + tstart;
  __shared__ __align__(16) float bcl[63 * 32];   // [t][16 s][2]
  for (int i = tid; i < nt * 32; i += 512) bcl[i] = ws[OFF_BC + rowbase * 32 + i];
  __syncthreads();
  const float2* __restrict__ packp = (const float2*)(ws + OFF_PACK) + rowbase * 512 + d;
  const float*  __restrict__ szp   = ws + OFF_SZ + rowbase * 512 + d;
  float h0 = 0.f, h1 = 0.f, cp0 = 1.f, cp1 = 1.f;
  float S10 = 0.f, S11 = 0.f, S20 = 0.f, S21 = 0.f, xacc = 0.f;
#pragma unroll 4
  for (int i = 0; i < nt; ++i) {
    float2 p  = packp[i * 512];     // (delta, xh) — coalesced, L1-shared
    float sz  = szp[i * 512];
    float4 bc = *(const float4*)&bcl[i * 32 + wv * 4];   // (B0,C0,B1,C1)
    float du = p.x * p.y;
    xacc = fmaf(p.y, sz, xacc);
    float e0 = __expf(p.x * a0), e1 = __expf(p.x * a1);
    cp0 *= e0; cp1 *= e1;
    h0 = fmaf(e0, h0, du * bc.x);
    h1 = fmaf(e1, h1, du * bc.z);
    float cs0 = bc.y * sz, cs1 = bc.w * sz;
    S10 = fmaf(h0, cs0, S10); S11 = fmaf(h1, cs1, S11);
    S20 = fmaf(cp0, cs0, S20); S21 = fmaf(cp1, cs1, S21);
  }
  {
    const int cbase = CHUNK_BASE(ck);
    const int s = wv * 2;
    int idx = (b * 16 + s) * 512 + d;             // [b][s][d] — coalesced
    *(float4*)&ws[cbase + idx * 4] = make_float4(cp0, h0, S10, S20);
    *(float4*)&ws[cbase + (idx + 512) * 4] = make_float4(cp1, h1, S11, S21);
  }
  if (wv == 0) ws[OFF_ACC16 + (ck * 8 + b) * 512 + d] = xacc;
}

// ================= K4: combine 16 chunks + s-reduce -> ybar =================
// grid (32 dg, 8 b) = 256 blocks; block 256 = 16 d x 16 s.
__global__ __launch_bounds__(256) void k4_scan2(const float* __restrict__ Dvec,
                                                float* __restrict__ ws) {
  const int dg = blockIdx.x;   // 32 groups of 16 d
  const int b  = blockIdx.y;
  const int tid = threadIdx.x;
  const int dl = tid & 15, s = tid >> 4;
  const int d = dg * 16 + dl;
  const int lane = tid & 63, wv = tid >> 6;
  float h = 0.f, y = 0.f;
#pragma unroll
  for (int k = 0; k < 16; ++k) {
    const float4 f = *(const float4*)&ws[CHUNK_BASE(k) + ((b * 16 + s) * 512 + d) * 4];
    y = fmaf(f.w, h, y + f.z);   // S1 + S2*h_in
    h = fmaf(f.x, h, f.y);       // P*h_in + q
  }
  // reduce over the 4 s-values within each wave (lane bits 4,5)
  y += __shfl_xor(y, 16);
  y += __shfl_xor(y, 32);
  __shared__ float ys[4][16];
  if (lane < 16) ys[wv][dl] = y;
  __syncthreads();
  if (tid < 16) {
    float yt = ys[0][tid] + ys[1][tid] + ys[2][tid] + ys[3][tid];
    float acc = 0.f;
#pragma unroll
    for (int k = 0; k < 16; ++k) acc += ws[OFF_ACC16 + (k * 8 + b) * 512 + dg * 16 + tid];
    int dd = dg * 16 + tid;
    ws[OFF_YBAR + b * 512 + dd] = yt + Dvec[dd] * acc;
  }
}

// ================= K5: out = ybar @ W2s.T + fc_b =================
__global__ __launch_bounds__(64) void k5_out(const float* __restrict__ fc_b,
                                             const float* __restrict__ ws,
                                             float* __restrict__ out) {
  const int b = blockIdx.x;
  const int n = threadIdx.x;
  if (n >= 35) return;
  const float* yb = ws + OFF_YBAR + b * 512;
  const float* w  = ws + OFF_W2S + n * 512;
  float sum = 0.f;
#pragma unroll 8
  for (int k = 0; k < 512; ++k) sum = fmaf(yb[k], w[k], sum);
  out[b * 35 + n] = sum + fc_b[n];
}

extern "C" void kernel_launch(void* const* d_in, const int* in_sizes, int n_in,
                              void* d_out, int out_size, void* d_ws, size_t ws_size,
                              hipStream_t stream) {
  const float* x          = (const float*)d_in[0];
  const float* proj_w     = (const float*)d_in[1];
  const float* proj_b     = (const float*)d_in[2];
  const float* in_proj_w  = (const float*)d_in[3];
  const float* conv_w     = (const float*)d_in[4];
  const float* conv_b     = (const float*)d_in[5];
  const float* x_proj_w   = (const float*)d_in[6];
  const float* dt_proj_w  = (const float*)d_in[7];
  const float* dt_proj_b  = (const float*)d_in[8];
  const float* A_log      = (const float*)d_in[9];
  const float* Dvec       = (const float*)d_in[10];
  const float* out_proj_w = (const float*)d_in[11];
  const float* fc_w       = (const float*)d_in[12];
  const float* fc_b       = (const float*)d_in[13];
  float* ws  = (float*)d_ws;
  float* out = (float*)d_out;
  if (ws_size < (size_t)WS_FLOATS * sizeof(float)) return;  // need ~76 MB scratch

  prep_w1t  <<<dim3(16, 5),    256, 0, stream>>>(proj_w, in_proj_w, ws);
  prep_small<<<106,            256, 0, stream>>>(proj_b, in_proj_w, fc_w, out_proj_w, A_log, ws);
  k1_xz     <<<dim3(4, 63, 8), 256, 0, stream>>>(x, conv_w, conv_b, ws);
  k2b_dbc   <<<dim3(500, 2),   256, 0, stream>>>(x_proj_w, ws);
  k2c_pack  <<<dim3(125, 8),   256, 0, stream>>>(dt_proj_w, dt_proj_b, ws);
  k3_scan1  <<<dim3(8, 16, 8), 512, 0, stream>>>(ws);
  k4_scan2  <<<dim3(32, 8),    256, 0, stream>>>(Dvec, ws);
  k5_out    <<<8,              64,  0, stream>>>(fc_b, ws, out);
}

// Round 8
// 164.150 us; speedup vs baseline: 1.5318x; 1.0011x over previous
//
#include <hip/hip_runtime.h>
#include <math.h>

// Problem constants
//  B=8, C_IN=80, T=1000, D_MODEL=256, D_INNER=512, D_STATE=16, DT_RANK=16,
//  D_CONV=4, N_LABELS=35

// ---- workspace layout (float offsets) ----
#define OFF_W1T   0          // [80][1024]  folded (in_proj@proj) transposed
#define OFF_B1    81920      // [1024]      folded bias
#define OFF_W2S   82944      // [35][512]   (fc_w@out_proj_w) * 1e-3 (mean fold)
#define OFF_AL2   100864     // [512][16]   A = -exp(A_log)
#define OFF_XH    109056     // [8000][512] silu(conv(xh)) — DEAD after k2c; reused for CHUNK ck<8 + ACC16
#define OFF_SZ    4205056    // [8000][512] silu(z)
#define OFF_PACK  8301056    // [8000][512] float2 (delta, xh)
#define OFF_BC    16493056   // [8000][16]  float2 (B, C)
#define OFF_CHUNK 16749056   // CHUNK ck>=8 region (2,097,152 floats)
#define OFF_DBCP  OFF_CHUNK  // [2ks][8000][48] k2b partials — dead before k3 writes here
#define OFF_YBAR  18878976   // [8][512]
#define WS_FLOATS 18883072   // ~75.5 MB

// 16 t-chunks: per-chunk block = 8b*16s*512d*4 floats
#define CK_FLOATS 262144
#define CHUNK_BASE(ck) ((ck) < 8 ? (OFF_XH + (ck) * CK_FLOATS) \
                                 : (OFF_CHUNK + ((ck) - 8) * CK_FLOATS))
#define OFF_ACC16 (OFF_XH + 2097152)   // [16ck][8b][512d] — inside dead XH region

__device__ __forceinline__ float silu_f(float v) {
  return v / (1.f + __expf(-v));
}

// ================= prep: folded weights =================
// W1T[c][n] = sum_m in_proj_w[n][m] * proj_w[m][c]   (M=80,N=1024,K=256)
__global__ __launch_bounds__(256) void prep_w1t(const float* __restrict__ proj_w,
                                                const float* __restrict__ in_proj_w,
                                                float* __restrict__ ws) {
  const int nt = blockIdx.x;          // 16 tiles of 64 n
  const int ct = blockIdx.y;          // 5 tiles of 16 c
  const int n0 = nt * 64, c0 = ct * 16;
  __shared__ float Pl[16 * 68];       // [c][k]
  __shared__ float Il[64 * 68];       // [k][n]
  const int tid = threadIdx.x;
  const int ng = tid & 31, cg = tid >> 5;   // 32 n-groups x2, 8 c-groups x2
  float acc[2][2] = {{0.f, 0.f}, {0.f, 0.f}};
  for (int kc = 0; kc < 256; kc += 64) {
    __syncthreads();
    for (int i = tid; i < 16 * 64; i += 256) {
      int k = i >> 4, c = i & 15;
      Pl[c * 68 + k] = proj_w[(kc + k) * 80 + c0 + c];
    }
    for (int i = tid; i < 64 * 64; i += 256) {
      int n = i >> 6, k = i & 63;
      Il[k * 68 + n] = in_proj_w[(n0 + n) * 256 + kc + k];
    }
    __syncthreads();
    for (int k = 0; k < 64; ++k) {
      float p0 = Pl[(cg * 2 + 0) * 68 + k];
      float p1 = Pl[(cg * 2 + 1) * 68 + k];
      float2 iv = *(const float2*)&Il[k * 68 + ng * 2];
      acc[0][0] = fmaf(p0, iv.x, acc[0][0]);
      acc[0][1] = fmaf(p0, iv.y, acc[0][1]);
      acc[1][0] = fmaf(p1, iv.x, acc[1][0]);
      acc[1][1] = fmaf(p1, iv.y, acc[1][1]);
    }
  }
  for (int r = 0; r < 2; ++r)
    for (int q = 0; q < 2; ++q)
      ws[OFF_W1T + (c0 + cg * 2 + r) * 1024 + n0 + ng * 2 + q] = acc[r][q];
}

// b1, W2s (scaled by 1/T), A
__global__ __launch_bounds__(256) void prep_small(const float* __restrict__ proj_b,
                                                  const float* __restrict__ in_proj_w,
                                                  const float* __restrict__ fc_w,
                                                  const float* __restrict__ out_proj_w,
                                                  const float* __restrict__ A_log,
                                                  float* __restrict__ ws) {
  int idx = blockIdx.x * 256 + threadIdx.x;
  if (idx < 1024) {
    float s = 0.f;
    for (int m = 0; m < 256; ++m) s = fmaf(in_proj_w[idx * 256 + m], proj_b[m], s);
    ws[OFF_B1 + idx] = s;
  } else if (idx < 1024 + 17920) {
    int j = idx - 1024;
    int n = j / 512, d = j - n * 512;   // consecutive threads -> consecutive d (coalesced)
    float s = 0.f;
    for (int m = 0; m < 256; ++m) s = fmaf(fc_w[n * 256 + m], out_proj_w[m * 512 + d], s);
    ws[OFF_W2S + j] = s * 1e-3f;        // fold mean over T=1000
  } else if (idx < 1024 + 17920 + 8192) {
    int j = idx - (1024 + 17920);
    ws[OFF_AL2 + j] = -expf(A_log[j]);
  }
}

// ================= K1: xz = X @ W1T + b1, x-tile in LDS (broadcast reads) ==
// Block = 256 threads = 256 consecutive n columns; 20-slot t-window
// (t0-4 .. t0+15), identical for the whole block. The 80x20 x-tile (6.4KB)
// is staged in LDS once (edge guards applied at staging); the inner loop
// reads it with wave-uniform ds_read_b128 (broadcast, conflict-free) so the
// pipeline depth is lgkmcnt-counted, not SGPR-limited (round-6: SGPR=96
// capped s_load prefetch at ~2 k-rows -> VALUBusy 37%).
// W1T loads per-lane coalesced (L2). Conv in registers.
__global__ __launch_bounds__(256) void k1_xz(const float* __restrict__ x,
                                             const float* __restrict__ conv_w,
                                             const float* __restrict__ conv_b,
                                             float* __restrict__ ws) {
  const int nt  = blockIdx.x;   // 4 tiles of 256 n
  const int tch = blockIdx.y;   // 63 chunks of 16 t
  const int b   = blockIdx.z;
  const int tid = threadIdx.x;
  const int n = nt * 256 + tid;        // global n column (0..1023)
  const int t0 = tch * 16;
  const int tbase = t0 - 4;            // acc[j] = xz at t = tbase + j

  __shared__ __align__(16) float xs[80 * 20];
  for (int i = tid; i < 1600; i += 256) {
    int k = i / 20, j = i - k * 20;
    int t = tbase + j;
    float v = 0.f;
    if (t >= 0 && t < 1000) v = x[(b * 80 + k) * 1000 + t];
    xs[i] = v;
  }
  __syncthreads();

  float acc[20];
  {
    const float b1v = ws[OFF_B1 + n];
#pragma unroll
    for (int j = 0; j < 20; ++j) acc[j] = b1v;
  }

  const float* __restrict__ w1t = ws + OFF_W1T;
  for (int kc = 0; kc < 80; kc += 8) {
    float wreg[8];
#pragma unroll
    for (int kk = 0; kk < 8; ++kk)
      wreg[kk] = w1t[(kc + kk) * 1024 + n];          // per-lane coalesced
#pragma unroll
    for (int kk = 0; kk < 8; ++kk) {
      const float w = wreg[kk];
      const float* xr = &xs[(kc + kk) * 20];         // uniform -> ds broadcast
#pragma unroll
      for (int g = 0; g < 5; ++g) {
        float4 xv = *(const float4*)(xr + g * 4);    // ds_read_b128, row is 80B
        acc[g * 4 + 0] = fmaf(xv.x, w, acc[g * 4 + 0]);
        acc[g * 4 + 1] = fmaf(xv.y, w, acc[g * 4 + 1]);
        acc[g * 4 + 2] = fmaf(xv.z, w, acc[g * 4 + 2]);
        acc[g * 4 + 3] = fmaf(xv.w, w, acc[g * 4 + 3]);
      }
    }
  }

  if (tch == 0) {
    // reference pads the PROJECTED sequence with zeros: xz[t<0] = 0
    acc[0] = 0.f; acc[1] = 0.f; acc[2] = 0.f; acc[3] = 0.f;
  }

  if (nt < 2) {
    // h-half: causal conv (taps t-3..t) + silu
    const int d = n;
    const float4 cw = *(const float4*)&conv_w[d * 4];
    const float cb = conv_b[d];
#pragma unroll
    for (int i = 0; i < 16; ++i) {
      int t = t0 + i;
      if (t < 1000) {
        float v = cb;
        v = fmaf(cw.x, acc[i + 1], v);   // xz[t-3]
        v = fmaf(cw.y, acc[i + 2], v);   // xz[t-2]
        v = fmaf(cw.z, acc[i + 3], v);   // xz[t-1]
        v = fmaf(cw.w, acc[i + 4], v);   // xz[t]
        ws[OFF_XH + (b * 1000 + t) * 512 + d] = silu_f(v);
      }
    }
  } else {
    const int d0 = n - 512;
#pragma unroll
    for (int i = 0; i < 16; ++i) {
      int t = t0 + i;
      if (t < 1000)
        ws[OFF_SZ + (b * 1000 + t) * 512 + d0] = silu_f(acc[i + 4]);
    }
  }
}

// ================= K2b: dbc partials = xh @ x_proj_w.T (split-K x2) =========
// grid (500 row-tiles of 16, 2 K-halves). 1000 blocks.
__global__ __launch_bounds__(256) void k2b_dbc(const float* __restrict__ x_proj_w,
                                               float* __restrict__ ws) {
  const int row0 = blockIdx.x * 16;
  const int ks   = blockIdx.y;          // K half
  const int k0   = ks * 256;
  __shared__ float Xl[16 * 68];
  __shared__ float Wl[48 * 68];
  const int tid = threadIdx.x;
  const int ng = tid & 15, rg = tid >> 4;   // 16 n-groups x3, 16 rows x1
  float acc[3] = {0.f, 0.f, 0.f};
  for (int kc = 0; kc < 256; kc += 64) {
    __syncthreads();
    for (int i = tid; i < 16 * 64; i += 256) {
      int r = i >> 6, c = i & 63;
      Xl[r * 68 + c] = ws[OFF_XH + (row0 + r) * 512 + k0 + kc + c];
    }
    for (int i = tid; i < 48 * 64; i += 256) {
      int r = i >> 6, c = i & 63;
      Wl[r * 68 + c] = x_proj_w[r * 512 + k0 + kc + c];
    }
    __syncthreads();
    for (int c = 0; c < 64; c += 4) {
      float4 xa = *(const float4*)&Xl[rg * 68 + c];
      float4 w0 = *(const float4*)&Wl[(ng * 3 + 0) * 68 + c];
      float4 w1 = *(const float4*)&Wl[(ng * 3 + 1) * 68 + c];
      float4 w2 = *(const float4*)&Wl[(ng * 3 + 2) * 68 + c];
      acc[0] += xa.x*w0.x + xa.y*w0.y + xa.z*w0.z + xa.w*w0.w;
      acc[1] += xa.x*w1.x + xa.y*w1.y + xa.z*w1.z + xa.w*w1.w;
      acc[2] += xa.x*w2.x + xa.y*w2.y + xa.z*w2.z + xa.w*w2.w;
    }
  }
  for (int n = 0; n < 3; ++n)
    ws[OFF_DBCP + ks * 384000 + (row0 + rg) * 48 + ng * 3 + n] = acc[n];
}

// ================= K2c: delta=softplus(dt@dtw+b); write pack(delta,xh), BC ==
__global__ __launch_bounds__(256) void k2c_pack(const float* __restrict__ dt_proj_w,
                                                const float* __restrict__ dt_proj_b,
                                                float* __restrict__ ws) {
  const int tb = blockIdx.x;   // 125 tiles of 8 t
  const int b  = blockIdx.y;
  const int tid = threadIdx.x;
  __shared__ float dbcl[8 * 48];
  for (int i = tid; i < 8 * 48; i += 256) {
    int tt = i / 48, c = i - tt * 48;
    int row = b * 1000 + tb * 8 + tt;
    dbcl[i] = ws[OFF_DBCP + row * 48 + c] + ws[OFF_DBCP + 384000 + row * 48 + c];
  }
  __syncthreads();
  if (tid < 128) {
    int tt = tid >> 4, s = tid & 15;
    int row = b * 1000 + tb * 8 + tt;
    *(float2*)&ws[OFF_BC + (row * 16 + s) * 2] =
        make_float2(dbcl[tt * 48 + 16 + s], dbcl[tt * 48 + 32 + s]);
  }
  for (int dd = tid; dd < 512; dd += 256) {
    const float4* wp = (const float4*)(dt_proj_w + dd * 16);
    float4 w0 = wp[0], w1 = wp[1], w2 = wp[2], w3 = wp[3];
    float bias = dt_proj_b[dd];
#pragma unroll
    for (int tt = 0; tt < 8; ++tt) {
      int row = b * 1000 + tb * 8 + tt;
      const float* dr = &dbcl[tt * 48];
      float lin = bias;
      lin = fmaf(dr[0],  w0.x, lin); lin = fmaf(dr[1],  w0.y, lin);
      lin = fmaf(dr[2],  w0.z, lin); lin = fmaf(dr[3],  w0.w, lin);
      lin = fmaf(dr[4],  w1.x, lin); lin = fmaf(dr[5],  w1.y, lin);
      lin = fmaf(dr[6],  w1.z, lin); lin = fmaf(dr[7],  w1.w, lin);
      lin = fmaf(dr[8],  w2.x, lin); lin = fmaf(dr[9],  w2.y, lin);
      lin = fmaf(dr[10], w2.z, lin); lin = fmaf(dr[11], w2.w, lin);
      lin = fmaf(dr[12], w3.x, lin); lin = fmaf(dr[13], w3.y, lin);
      lin = fmaf(dr[14], w3.z, lin); lin = fmaf(dr[15], w3.w, lin);
      float delta = fmaxf(lin, 0.f) + log1pf(__expf(-fabsf(lin)));  // softplus
      float xh = ws[OFF_XH + row * 512 + dd];
      *(float2*)&ws[OFF_PACK + (row * 512 + dd) * 2] = make_float2(delta, xh);
    }
  }
}

// ================= K3: chunked scan pass 1 (d-major, 16 t-chunks) ===========
// block 512 = 64 d-lanes x 8 waves; TWO s-chains per thread (s = wv*2+{0,1}).
// grid (8 dg, 16 ck, 8 b) = 1024 blocks x 8 waves = 32 waves/CU.
// The 8 waves of a block read IDENTICAL pack/sz lines -> L1-served after
// first toucher. BC chunk staged in LDS. Simple rolled loop (compiler
// pipelines; manual 5-wide dbuf inflated VGPR to 128 in round 5).
__global__ __launch_bounds__(512) void k3_scan1(float* __restrict__ ws) {
  const int dg = blockIdx.x;          // 8 groups of 64 d
  const int ck = blockIdx.y;          // 16 t-chunks (63 for ck<8, else 62)
  const int b  = blockIdx.z;
  const int tid = threadIdx.x;
  const int lane = tid & 63;          // d within group
  const int wv = tid >> 6;            // 0..7; s = wv*2 + {0,1}
  const int d = dg * 64 + lane;
  const float2 av = *(const float2*)&ws[OFF_AL2 + d * 16 + wv * 2];
  const float a0 = av.x, a1 = av.y;
  const int nt = (ck < 8) ? 63 : 62;
  const int tstart = (ck < 8) ? 63 * ck : 62 * ck + 8;
  const int rowbase = b * 1000 + tstart;
  __shared__ __align__(16) float bcl[63 * 32];   // [t][16 s][2]
  for (int i = tid; i < nt * 32; i += 512) bcl[i] = ws[OFF_BC + rowbase * 32 + i];
  __syncthreads();
  const float2* __restrict__ packp = (const float2*)(ws + OFF_PACK) + rowbase * 512 + d;
  const float*  __restrict__ szp   = ws + OFF_SZ + rowbase * 512 + d;
  float h0 = 0.f, h1 = 0.f, cp0 = 1.f, cp1 = 1.f;
  float S10 = 0.f, S11 = 0.f, S20 = 0.f, S21 = 0.f, xacc = 0.f;
#pragma unroll 4
  for (int i = 0; i < nt; ++i) {
    float2 p  = packp[i * 512];     // (delta, xh) — coalesced, L1-shared
    float sz  = szp[i * 512];
    float4 bc = *(const float4*)&bcl[i * 32 + wv * 4];   // (B0,C0,B1,C1)
    float du = p.x * p.y;
    xacc = fmaf(p.y, sz, xacc);
    float e0 = __expf(p.x * a0), e1 = __expf(p.x * a1);
    cp0 *= e0; cp1 *= e1;
    h0 = fmaf(e0, h0, du * bc.x);
    h1 = fmaf(e1, h1, du * bc.z);
    float cs0 = bc.y * sz, cs1 = bc.w * sz;
    S10 = fmaf(h0, cs0, S10); S11 = fmaf(h1, cs1, S11);
    S20 = fmaf(cp0, cs0, S20); S21 = fmaf(cp1, cs1, S21);
  }
  {
    const int cbase = CHUNK_BASE(ck);
    const int s = wv * 2;
    int idx = (b * 16 + s) * 512 + d;             // [b][s][d] — coalesced
    *(float4*)&ws[cbase + idx * 4] = make_float4(cp0, h0, S10, S20);
    *(float4*)&ws[cbase + (idx + 512) * 4] = make_float4(cp1, h1, S11, S21);
  }
  if (wv == 0) ws[OFF_ACC16 + (ck * 8 + b) * 512 + d] = xacc;
}

// ================= K4: combine 16 chunks + s-reduce -> ybar =================
// grid (32 dg, 8 b) = 256 blocks; block 256 = 16 d x 16 s.
__global__ __launch_bounds__(256) void k4_scan2(const float* __restrict__ Dvec,
                                                float* __restrict__ ws) {
  const int dg = blockIdx.x;   // 32 groups of 16 d
  const int b  = blockIdx.y;
  const int tid = threadIdx.x;
  const int dl = tid & 15, s = tid >> 4;
  const int d = dg * 16 + dl;
  const int lane = tid & 63, wv = tid >> 6;
  float h = 0.f, y = 0.f;
#pragma unroll
  for (int k = 0; k < 16; ++k) {
    const float4 f = *(const float4*)&ws[CHUNK_BASE(k) + ((b * 16 + s) * 512 + d) * 4];
    y = fmaf(f.w, h, y + f.z);   // S1 + S2*h_in
    h = fmaf(f.x, h, f.y);       // P*h_in + q
  }
  // reduce over the 4 s-values within each wave (lane bits 4,5)
  y += __shfl_xor(y, 16);
  y += __shfl_xor(y, 32);
  __shared__ float ys[4][16];
  if (lane < 16) ys[wv][dl] = y;
  __syncthreads();
  if (tid < 16) {
    float yt = ys[0][tid] + ys[1][tid] + ys[2][tid] + ys[3][tid];
    float acc = 0.f;
#pragma unroll
    for (int k = 0; k < 16; ++k) acc += ws[OFF_ACC16 + (k * 8 + b) * 512 + dg * 16 + tid];
    int dd = dg * 16 + tid;
    ws[OFF_YBAR + b * 512 + dd] = yt + Dvec[dd] * acc;
  }
}

// ================= K5: out = ybar @ W2s.T + fc_b =================
__global__ __launch_bounds__(64) void k5_out(const float* __restrict__ fc_b,
                                             const float* __restrict__ ws,
                                             float* __restrict__ out) {
  const int b = blockIdx.x;
  const int n = threadIdx.x;
  if (n >= 35) return;
  const float* yb = ws + OFF_YBAR + b * 512;
  const float* w  = ws + OFF_W2S + n * 512;
  float sum = 0.f;
#pragma unroll 8
  for (int k = 0; k < 512; ++k) sum = fmaf(yb[k], w[k], sum);
  out[b * 35 + n] = sum + fc_b[n];
}

extern "C" void kernel_launch(void* const* d_in, const int* in_sizes, int n_in,
                              void* d_out, int out_size, void* d_ws, size_t ws_size,
                              hipStream_t stream) {
  const float* x          = (const float*)d_in[0];
  const float* proj_w     = (const float*)d_in[1];
  const float* proj_b     = (const float*)d_in[2];
  const float* in_proj_w  = (const float*)d_in[3];
  const float* conv_w     = (const float*)d_in[4];
  const float* conv_b     = (const float*)d_in[5];
  const float* x_proj_w   = (const float*)d_in[6];
  const float* dt_proj_w  = (const float*)d_in[7];
  const float* dt_proj_b  = (const float*)d_in[8];
  const float* A_log      = (const float*)d_in[9];
  const float* Dvec       = (const float*)d_in[10];
  const float* out_proj_w = (const float*)d_in[11];
  const float* fc_w       = (const float*)d_in[12];
  const float* fc_b       = (const float*)d_in[13];
  float* ws  = (float*)d_ws;
  float* out = (float*)d_out;
  if (ws_size < (size_t)WS_FLOATS * sizeof(float)) return;  // need ~76 MB scratch

  prep_w1t  <<<dim3(16, 5),    256, 0, stream>>>(proj_w, in_proj_w, ws);
  prep_small<<<106,            256, 0, stream>>>(proj_b, in_proj_w, fc_w, out_proj_w, A_log, ws);
  k1_xz     <<<dim3(4, 63, 8), 256, 0, stream>>>(x, conv_w, conv_b, ws);
  k2b_dbc   <<<dim3(500, 2),   256, 0, stream>>>(x_proj_w, ws);
  k2c_pack  <<<dim3(125, 8),   256, 0, stream>>>(dt_proj_w, dt_proj_b, ws);
  k3_scan1  <<<dim3(8, 16, 8), 512, 0, stream>>>(ws);
  k4_scan2  <<<dim3(32, 8),    256, 0, stream>>>(Dvec, ws);
  k5_out    <<<8,              64,  0, stream>>>(fc_b, ws, out);
}